// Round 8
// baseline (313.079 us; speedup 1.0000x reference)
//
#include <hip/hip_runtime.h>
#include <hip/hip_bf16.h>
#include <math.h>

#define D 128
#define NUM_GRAPHS 64
#define CHUNK 8192          // edges per binning block
#define BUCK_SH 8           // bucket = col >> 8  (256 nodes per bucket)
#define BUCK_N 256
#define BCAP 8192           // fixed slot capacity per bucket (mean 4096, +64 sigma)
#define PSLICE 8            // pooling blocks per graph
#define HROW 136            // LDS row stride (17x16B) for h1 tile

typedef __bf16 bf16x8 __attribute__((ext_vector_type(8)));
typedef __bf16 bf16x2 __attribute__((ext_vector_type(2)));
typedef float f32x4 __attribute__((ext_vector_type(4)));
typedef float f32x2 __attribute__((ext_vector_type(2)));

// fp8 e4m3 (OCP) helpers — HW converts on gfx950
__device__ inline unsigned char f32_to_fp8(float x) {
    int pk = __builtin_amdgcn_cvt_pk_fp8_f32(x, x, 0, false);
    return (unsigned char)(pk & 0xff);
}
// word-select operand must be a compile-time constant (round-6 lesson)
template <bool HI>
__device__ inline f32x2 fp8x2_to_f32(unsigned int us) {
    return __builtin_amdgcn_cvt_pk_f32_fp8(us, HI);
}
__device__ inline f32x2 fp8x2_to_f32_us(unsigned short us) {
    return __builtin_amdgcn_cvt_pk_f32_fp8((unsigned int)us, false);
}

// ---------------- W -> bf16 B-fragment pack; zero pooled/done/gcur; graph bounds ----------------
__global__ void k_prepW(const float* __restrict__ Wa, const float* __restrict__ Wb,
                        __bf16* __restrict__ WfA, __bf16* __restrict__ WfB,
                        float* __restrict__ pooled, int* __restrict__ done,
                        int* __restrict__ gcur,
                        const int* __restrict__ batch, int* __restrict__ gstart, int N) {
    int gid = blockIdx.x * 256 + threadIdx.x;   // 0..33023
    if (gid < NUM_GRAPHS * D) pooled[gid] = 0.f;
    if (gid == 0) *done = 0;
    if (gid < 512) gcur[gid] = 0;
    if (gid >= 16384 && gid <= 16384 + NUM_GRAPHS) {   // 65 threads do binary search
        int g = gid - 16384;
        int lo = 0, hi = N;
        while (lo < hi) { int mid = (lo + hi) >> 1; if (batch[mid] < g) lo = mid + 1; else hi = mid; }
        gstart[g] = lo;
    }
    if (gid >= 32768) return;
    const float* W = (gid < 16384) ? Wa : Wb;
    __bf16* Wf = (gid < 16384) ? WfA : WfB;
    int idx = gid & 16383;
    int j = idx & 7, lane = (idx >> 3) & 63, kc = (idx >> 9) & 3, ft = idx >> 11;
    int k = kc * 32 + (lane >> 4) * 8 + j;
    int f = ft * 16 + (lane & 15);
    Wf[idx] = (__bf16)W[k * D + f];
}

// ---------------- MFMA GEMM body: Y8[N,128](fp8) = X[N,128] @ W  (UNSCALED) ----------------
template <typename T>
__device__ __forceinline__ void gemm_body(int bid, int tid, const T* __restrict__ X,
                                          const __bf16* __restrict__ Wfrag,
                                          unsigned char* __restrict__ Y8, int N) {
    int w = tid >> 6, lane = tid & 63;
    int quad = lane >> 4, m = lane & 15;
    int nodeA = bid * 64 + w * 16 + m;
    if (nodeA >= N) nodeA = N - 1;

    bf16x8 a[4];
#pragma unroll
    for (int kc = 0; kc < 4; kc++) {
        int kb = kc * 32 + quad * 8;
        if constexpr (sizeof(T) == 4) {
            f32x4 x0 = *(const f32x4*)(X + (size_t)nodeA * D + kb);
            f32x4 x1 = *(const f32x4*)(X + (size_t)nodeA * D + kb + 4);
#pragma unroll
            for (int j = 0; j < 4; j++) { a[kc][j] = (__bf16)x0[j]; a[kc][4 + j] = (__bf16)x1[j]; }
        } else {
            a[kc] = *(const bf16x8*)(X + (size_t)nodeA * D + kb);
        }
    }

    f32x4 d[8];
#pragma unroll
    for (int ft = 0; ft < 8; ft++) {
        d[ft] = (f32x4){0.f, 0.f, 0.f, 0.f};
#pragma unroll
        for (int kc = 0; kc < 4; kc++) {
            bf16x8 b = *(const bf16x8*)(Wfrag + (((ft << 2) | kc) * 64 + lane) * 8);
            d[ft] = __builtin_amdgcn_mfma_f32_16x16x32_bf16(a[kc], b, d[ft], 0, 0, 0);
        }
    }

#pragma unroll
    for (int r = 0; r < 4; r++) {
        int node = bid * 64 + w * 16 + quad * 4 + r;
        if (node < N) {
#pragma unroll
            for (int ft = 0; ft < 8; ft++)
                Y8[(size_t)node * D + ft * 16 + m] = f32_to_fp8(d[ft][r]);
        }
    }
}

// ---------------- FUSED: CSR bin pass (blocks [0,nchunk)) + layer-1 GEMM (rest) ----------------
__launch_bounds__(256)
__global__ void k_bin_gemm(const int* __restrict__ ei, int* __restrict__ gcur,
                           int* __restrict__ bbuf, int nbuck, int E, int nchunk,
                           const float* __restrict__ X, const __bf16* __restrict__ Wfrag,
                           unsigned char* __restrict__ Y8, int N) {
    __shared__ int h[512];
    __shared__ int base[512];

    if (blockIdx.x >= nchunk) {
        gemm_body<float>(blockIdx.x - nchunk, threadIdx.x, X, Wfrag, Y8, N);
        return;
    }

    int tid = threadIdx.x;
    for (int b = tid; b < nbuck; b += 256) h[b] = 0;
    __syncthreads();
    int lo = blockIdx.x * CHUNK;
    if (lo + CHUNK <= E) {
        const int4* c4 = (const int4*)(ei + E + lo);
#pragma unroll 2
        for (int i = tid; i < CHUNK / 4; i += 256) {
            int4 c = c4[i];
            atomicAdd(&h[c.x >> BUCK_SH], 1);
            atomicAdd(&h[c.y >> BUCK_SH], 1);
            atomicAdd(&h[c.z >> BUCK_SH], 1);
            atomicAdd(&h[c.w >> BUCK_SH], 1);
        }
    } else {
        for (int i = tid; i < CHUNK; i += 256) {
            int e = lo + i;
            if (e < E) atomicAdd(&h[ei[E + e] >> BUCK_SH], 1);
        }
    }
    __syncthreads();
    for (int b = tid; b < nbuck; b += 256) {
        base[b] = atomicAdd(&gcur[b], h[b]);
        h[b] = 0;
    }
    __syncthreads();
    if (lo + CHUNK <= E) {
        const int4* r4 = (const int4*)(ei + lo);
        const int4* c4 = (const int4*)(ei + E + lo);
#pragma unroll 2
        for (int i = tid; i < CHUNK / 4; i += 256) {
            int4 r = r4[i];
            int4 c = c4[i];
            int rr[4] = {r.x, r.y, r.z, r.w};
            int cc[4] = {c.x, c.y, c.z, c.w};
#pragma unroll
            for (int u = 0; u < 4; u++) {
                int b = cc[u] >> BUCK_SH;
                int pos = base[b] + atomicAdd(&h[b], 1);
                if (pos < BCAP) bbuf[(size_t)b * BCAP + pos] = rr[u] | ((cc[u] & (BUCK_N - 1)) << 17);
            }
        }
    } else {
        for (int i = tid; i < CHUNK; i += 256) {
            int e = lo + i;
            if (e < E) {
                int r = ei[e], c = ei[E + e];
                int b = c >> BUCK_SH;
                int pos = base[b] + atomicAdd(&h[b], 1);
                if (pos < BCAP) bbuf[(size_t)b * BCAP + pos] = r | ((c & (BUCK_N - 1)) << 17);
            }
        }
    }
}

// ---------------- CSR build pass 2 + IN-PLACE z1 SCALING ----------------
// Bucket b owns nodes [256b, 256b+256) — exactly the rows whose dis this block
// computes. Epilogue rescales those z1 rows in place (fp8 -> f32 -> *dis -> fp8)
// so the agg kernels get the lean r0 inner loop (no per-edge dis shuffle).
__global__ void k_place(const int* __restrict__ bbuf, const int* __restrict__ gcur,
                        int* __restrict__ esrc,
                        int* __restrict__ cnt, int* __restrict__ offs,
                        float* __restrict__ dis, unsigned char* __restrict__ z1, int N) {
    __shared__ int h[256];
    __shared__ int sc[256];
    __shared__ int cur[256];
    __shared__ float sdis[256];
    int b = blockIdx.x, tid = threadIdx.x;
    int start = b * BCAP;
    int count = gcur[b]; if (count > BCAP) count = BCAP;
    int end = start + count;
    h[tid] = 0;
    __syncthreads();
    for (int i = start + tid; i < end; i += 256) atomicAdd(&h[(bbuf[i] >> 17) & 255], 1);
    __syncthreads();
    int local = h[tid];
    sc[tid] = local;
    __syncthreads();
    for (int off = 1; off < 256; off <<= 1) {
        int xv = (tid >= off) ? sc[tid - off] : 0;
        __syncthreads();
        sc[tid] += xv;
        __syncthreads();
    }
    int excl = sc[tid] - local;
    cur[tid] = start + excl;
    int c = b * 256 + tid;
    float dv = rsqrtf(1.0f + (float)local);
    sdis[tid] = dv;
    if (c < N) {
        cnt[c]  = local;
        offs[c] = start + excl;
        dis[c]  = dv;                        // deg includes self-loop
    }
    __syncthreads();
    for (int i = start + tid; i < end; i += 256) {
        int p = bbuf[i];
        int pos = atomicAdd(&cur[(p >> 17) & 255], 1);
        esrc[pos] = p & 0x1FFFF;
    }
    // ---- in-place scale of this bucket's z1 rows ----
    int nrows = N - b * 256; if (nrows > 256) nrows = 256; if (nrows < 0) nrows = 0;
    unsigned int* zp = (unsigned int*)(z1 + (size_t)b * 256 * D);
    for (int i = tid; i < nrows * 32; i += 256) {      // 32 dwords per 128B row
        int row = i >> 5;
        float s = sdis[row];
        unsigned int v = zp[i];
        f32x2 lo = fp8x2_to_f32<false>(v);
        f32x2 hi = fp8x2_to_f32<true>(v);
        unsigned int u = (unsigned int)__builtin_amdgcn_cvt_pk_fp8_f32(lo[0] * s, lo[1] * s, 0, false);
        u = (unsigned int)__builtin_amdgcn_cvt_pk_fp8_f32(hi[0] * s, hi[1] * s, (int)u, true);
        zp[i] = u;
    }
}

// ---------------- FUSED layer-1 agg + GEMM2: z2 = fp8(dis .* (leaky(agg(z1)+b1) @ W2)) ----------------
// z1 rows are PRE-SCALED (k_place epilogue) -> lean r0 inner loop (1 shfl/edge).
// h1 rows go to LDS (never to global); MFMA phase computes h1 @ W2, epilogue
// scales by dis[node] and writes fp8 z2.
__launch_bounds__(256)
__global__ void k_agg_gemm(const unsigned char* __restrict__ Hs8,      // z1 scaled fp8
                           const int* __restrict__ offs, const int* __restrict__ cnt,
                           const float* __restrict__ dis, const int* __restrict__ esrc,
                           const float* __restrict__ bias,             // b1
                           const __bf16* __restrict__ Wfrag,           // Wf2
                           unsigned char* __restrict__ Y8, int N) {    // z2 scaled fp8
    __shared__ __bf16 hl[32 * HROW];   // 32 nodes x 128 feats, padded rows (17x16B)
    int tid = threadIdx.x;
    int w = tid >> 6, lane = tid & 63;
    int node0 = blockIdx.x * 32 + w * 8;
    float b0 = bias[lane * 2], b1v = bias[lane * 2 + 1];

    for (int nn = 0; nn < 8; nn++) {
        int node = node0 + nn;
        if (node < N) {
            int start = offs[node];
            int len = cnt[node];
            float di = dis[node];
            f32x2 h = fp8x2_to_f32_us(*(const unsigned short*)(Hs8 + (size_t)node * D + lane * 2));
            float acc0 = h[0];               // self-loop term (already dis-scaled)
            float acc1 = h[1];

            for (int k0 = 0; k0 < len; k0 += 64) {
                int mm = len - k0; if (mm > 64) mm = 64;
                int ep = esrc[start + k0 + (lane < mm ? lane : 0)];
                int j = 0;
                for (; j + 16 <= mm; j += 16) {
                    int s[16]; unsigned short hv[16];
#pragma unroll
                    for (int u = 0; u < 16; u++) s[u] = __shfl(ep, j + u);
#pragma unroll
                    for (int u = 0; u < 16; u++) hv[u] = *(const unsigned short*)(Hs8 + (size_t)s[u] * D + lane * 2);
#pragma unroll
                    for (int u = 0; u < 16; u++) { f32x2 f = fp8x2_to_f32_us(hv[u]); acc0 += f[0]; acc1 += f[1]; }
                }
                for (; j + 4 <= mm; j += 4) {
                    int s[4]; unsigned short hv[4];
#pragma unroll
                    for (int u = 0; u < 4; u++) s[u] = __shfl(ep, j + u);
#pragma unroll
                    for (int u = 0; u < 4; u++) hv[u] = *(const unsigned short*)(Hs8 + (size_t)s[u] * D + lane * 2);
#pragma unroll
                    for (int u = 0; u < 4; u++) { f32x2 f = fp8x2_to_f32_us(hv[u]); acc0 += f[0]; acc1 += f[1]; }
                }
                for (; j < mm; j++) {
                    int s = __shfl(ep, j);
                    f32x2 f = fp8x2_to_f32_us(*(const unsigned short*)(Hs8 + (size_t)s * D + lane * 2));
                    acc0 += f[0]; acc1 += f[1];
                }
            }

            acc0 = acc0 * di + b0;
            acc1 = acc1 * di + b1v;
            acc0 = acc0 >= 0.f ? acc0 : 0.01f * acc0;
            acc1 = acc1 >= 0.f ? acc1 : 0.01f * acc1;
            bf16x2 o; o[0] = (__bf16)acc0; o[1] = (__bf16)acc1;
            *(bf16x2*)&hl[(w * 8 + nn) * HROW + lane * 2] = o;   // h1 -> LDS only
        } else {
            bf16x2 z; z[0] = (__bf16)0.f; z[1] = (__bf16)0.f;
            *(bf16x2*)&hl[(w * 8 + nn) * HROW + lane * 2] = z;
        }
    }
    __syncthreads();

    // ---- MFMA phase: wave w -> row tile (w&1)*16, ft half (w>>1)*4 ----
    int quad = lane >> 4, m = lane & 15;
    int rtile = w & 1, fthalf = w >> 1;
    int lrow = rtile * 16 + m;
    bf16x8 a[4];
#pragma unroll
    for (int kc = 0; kc < 4; kc++)
        a[kc] = *(const bf16x8*)&hl[lrow * HROW + kc * 32 + quad * 8];

    int nb = blockIdx.x * 32 + rtile * 16 + quad * 4;
    float scv[4];
#pragma unroll
    for (int r = 0; r < 4; r++) scv[r] = (nb + r < N) ? dis[nb + r] : 0.f;

#pragma unroll
    for (int ft = 0; ft < 4; ft++) {
        int gft = fthalf * 4 + ft;
        f32x4 dacc = (f32x4){0.f, 0.f, 0.f, 0.f};
#pragma unroll
        for (int kc = 0; kc < 4; kc++) {
            bf16x8 b = *(const bf16x8*)(Wfrag + (((gft << 2) | kc) * 64 + lane) * 8);
            dacc = __builtin_amdgcn_mfma_f32_16x16x32_bf16(a[kc], b, dacc, 0, 0, 0);
        }
#pragma unroll
        for (int r = 0; r < 4; r++) {
            int node = nb + r;
            if (node < N)
                Y8[(size_t)node * D + gft * 16 + m] = f32_to_fp8(dacc[r] * scv[r]);
        }
    }
}

// ---------------- layer-2 CSR aggregation + bias + leaky ReLU (r0 lean loop) ----------------
__launch_bounds__(256)
__global__ void k_agg(const unsigned char* __restrict__ Hs8, __bf16* __restrict__ O,
                      const int* __restrict__ offs, const int* __restrict__ cnt,
                      const float* __restrict__ dis, const int* __restrict__ esrc,
                      const float* __restrict__ bias, int N) {
    int wave = (blockIdx.x * 256 + threadIdx.x) >> 6;
    int lane = threadIdx.x & 63;
    int node0 = wave * 8;
    float b0 = bias[lane * 2], b1 = bias[lane * 2 + 1];

    for (int nn = 0; nn < 8; nn++) {
        int node = node0 + nn;
        if (node >= N) return;
        int start = offs[node];
        int len = cnt[node];
        float di = dis[node];
        f32x2 h = fp8x2_to_f32_us(*(const unsigned short*)(Hs8 + (size_t)node * D + lane * 2));
        float acc0 = h[0];               // self-loop term (already dis-scaled)
        float acc1 = h[1];

        for (int k0 = 0; k0 < len; k0 += 64) {
            int mm = len - k0; if (mm > 64) mm = 64;
            int ep = esrc[start + k0 + (lane < mm ? lane : 0)];
            int j = 0;
            for (; j + 16 <= mm; j += 16) {
                int s[16]; unsigned short hv[16];
#pragma unroll
                for (int u = 0; u < 16; u++) s[u] = __shfl(ep, j + u);
#pragma unroll
                for (int u = 0; u < 16; u++) hv[u] = *(const unsigned short*)(Hs8 + (size_t)s[u] * D + lane * 2);
#pragma unroll
                for (int u = 0; u < 16; u++) { f32x2 f = fp8x2_to_f32_us(hv[u]); acc0 += f[0]; acc1 += f[1]; }
            }
            for (; j + 4 <= mm; j += 4) {
                int s[4]; unsigned short hv[4];
#pragma unroll
                for (int u = 0; u < 4; u++) s[u] = __shfl(ep, j + u);
#pragma unroll
                for (int u = 0; u < 4; u++) hv[u] = *(const unsigned short*)(Hs8 + (size_t)s[u] * D + lane * 2);
#pragma unroll
                for (int u = 0; u < 4; u++) { f32x2 f = fp8x2_to_f32_us(hv[u]); acc0 += f[0]; acc1 += f[1]; }
            }
            for (; j < mm; j++) {
                int s = __shfl(ep, j);
                f32x2 f = fp8x2_to_f32_us(*(const unsigned short*)(Hs8 + (size_t)s * D + lane * 2));
                acc0 += f[0]; acc1 += f[1];
            }
        }

        acc0 = acc0 * di + b0;
        acc1 = acc1 * di + b1;
        acc0 = acc0 >= 0.f ? acc0 : 0.01f * acc0;
        acc1 = acc1 >= 0.f ? acc1 : 0.01f * acc1;
        bf16x2 o; o[0] = (__bf16)acc0; o[1] = (__bf16)acc1;
        *(bf16x2*)(O + (size_t)node * D + lane * 2) = o;
    }
}

// ---------------- pooling: per-graph-slice vectorized reduction + fused FC (r0-proven) ----------------
__launch_bounds__(256)
__global__ void k_pool(const __bf16* __restrict__ H, const int* __restrict__ gstart,
                       float* __restrict__ pooled,
                       const float* __restrict__ fcW, const float* __restrict__ fcb,
                       float* __restrict__ out, int* __restrict__ done) {
    __shared__ float sdata[256 * 9];
    __shared__ int lastflag;
    int g = blockIdx.x / PSLICE;
    int slice = blockIdx.x - g * PSLICE;
    int gs = gstart[g], ge = gstart[g + 1];
    int cg = ge - gs;
    int r0 = gs + (int)((long long)cg * slice / PSLICE);
    int r1 = gs + (int)((long long)cg * (slice + 1) / PSLICE);
    int t = threadIdx.x;
    int rg = t >> 4, fb = t & 15;

    float acc[8];
#pragma unroll
    for (int j = 0; j < 8; j++) acc[j] = 0.f;
    for (int r = r0 + rg; r < r1; r += 16) {
        bf16x8 v = *(const bf16x8*)(H + (size_t)r * D + fb * 8);
#pragma unroll
        for (int j = 0; j < 8; j++) acc[j] += (float)v[j];
    }
#pragma unroll
    for (int j = 0; j < 8; j++) sdata[t * 9 + j] = acc[j];
    __syncthreads();
#pragma unroll
    for (int s = 128; s >= 16; s >>= 1) {
        if (t < s) {
#pragma unroll
            for (int j = 0; j < 8; j++) sdata[t * 9 + j] += sdata[(t + s) * 9 + j];
        }
        __syncthreads();
    }
    if (t < 16) {
#pragma unroll
        for (int j = 0; j < 8; j++) atomicAdd(&pooled[g * D + t * 8 + j], sdata[t * 9 + j]);
    }
    __threadfence();
    __syncthreads();
    if (t == 0) lastflag = (atomicAdd(done, 1) == (int)gridDim.x - 1) ? 1 : 0;
    __syncthreads();
    if (lastflag) {
        __threadfence();
        if (t < NUM_GRAPHS) {
            float s = 0.f;
#pragma unroll 4
            for (int k = 0; k < D; k++) s += pooled[t * D + k] * fcW[k];
            float c = (float)(gstart[t + 1] - gstart[t]);
            out[t] = s / fmaxf(c, 1.0f) + fcb[0];
        }
    }
}

extern "C" void kernel_launch(void* const* d_in, const int* in_sizes, int n_in,
                              void* d_out, int out_size, void* d_ws, size_t ws_size,
                              hipStream_t stream) {
    const float* x    = (const float*)d_in[0];
    const int*   ei   = (const int*)d_in[1];
    const int*   batch= (const int*)d_in[2];
    const float* W1   = (const float*)d_in[3];
    const float* b1   = (const float*)d_in[4];
    const float* W2   = (const float*)d_in[5];
    const float* b2   = (const float*)d_in[6];
    const float* fcW  = (const float*)d_in[7];
    const float* fcb  = (const float*)d_in[8];
    float* out = (float*)d_out;

    int N = in_sizes[0] / D;
    int E = in_sizes[1] / 2;

    int NBUCK  = (N + BUCK_N - 1) >> BUCK_SH;  // 391 for N=100000 (<=512)
    int NCHUNK = (E + CHUNK - 1) / CHUNK;      // 196 for E=1.6M

    char* p = (char*)d_ws;
    auto alloc = [&](size_t bytes) { char* r = p; p += (bytes + 255) & ~(size_t)255; return r; };
    int*    cnt    = (int*)   alloc((size_t)N * 4);
    int*    offs   = (int*)   alloc((size_t)N * 4);
    float*  dis    = (float*) alloc((size_t)N * 4);
    int*    gcur   = (int*)   alloc(512 * 4);
    int*    bbuf   = (int*)   alloc((size_t)NBUCK * BCAP * 4);
    int*    esrc   = (int*)   alloc((size_t)NBUCK * BCAP * 4);
    unsigned char* bufA8 = (unsigned char*)alloc((size_t)(NBUCK * BUCK_N) * D); // z1 fp8 (scaled in place)
    unsigned char* bufC8 = (unsigned char*)alloc((size_t)N * D);   // z2 fp8 (scaled)
    __bf16* bufB   = (__bf16*)alloc((size_t)N * D * 2);            // h2 bf16
    __bf16* Wf1    = (__bf16*)alloc((size_t)D * D * 2);
    __bf16* Wf2    = (__bf16*)alloc((size_t)D * D * 2);
    float*  pooled = (float*) alloc((size_t)NUM_GRAPHS * D * 4);
    int*    gstart = (int*)   alloc((NUM_GRAPHS + 1) * 4);
    int*    done   = (int*)   alloc(256);

    int gblocks = (N + 63) / 64;
    int ablocks = (N + 31) / 32;     // agg kernels: 4 waves/block x 8 nodes/wave

    // prep: zeroes gcur/pooled/done, packs W, graph boundaries
    k_prepW<<<129, 256, 0, stream>>>(W1, W2, Wf1, Wf2, pooled, done, gcur, batch, gstart, N);

    // FUSED: CSR bin (196 blocks) runs concurrently with layer-1 GEMM (1563 blocks)
    k_bin_gemm<<<NCHUNK + gblocks, 256, 0, stream>>>(ei, gcur, bbuf, NBUCK, E, NCHUNK,
                                                     x, Wf1, bufA8, N);
    // CSR place + in-place dis-scaling of z1 rows (bucket b owns nodes 256b..)
    k_place<<<NBUCK, 256, 0, stream>>>(bbuf, gcur, esrc, cnt, offs, dis, bufA8, N);

    // FUSED layer-1 agg + GEMM2: bufC8 = fp8(dis .* (leaky(agg(bufA8)+b1) @ W2))
    k_agg_gemm<<<ablocks, 256, 0, stream>>>(bufA8, offs, cnt, dis, esrc, b1, Wf2, bufC8, N);

    // layer-2 agg (lean): bufB = leaky(agg(bufC8)+b2)
    k_agg<<<ablocks, 256, 0, stream>>>(bufC8, bufB, offs, cnt, dis, esrc, b2, N);

    // pool + fused FC (done-counter; 512-block fence measured harmless in r0)
    k_pool<<<NUM_GRAPHS * PSLICE, 256, 0, stream>>>(bufB, gstart, pooled, fcW, fcb, out, done);
}

// Round 9
// 283.082 us; speedup vs baseline: 1.1060x; 1.1060x over previous
//
#include <hip/hip_runtime.h>
#include <hip/hip_bf16.h>
#include <math.h>

#define D 128
#define NUM_GRAPHS 64
#define CHUNK 8192          // edges per binning block
#define BUCK_SH 8           // bucket = col >> 8  (256 nodes per bucket)
#define BUCK_N 256
#define BCAP 8192           // fixed slot capacity per bucket (mean 4096, +64 sigma)
#define PSLICE 8            // pooling blocks per graph
#define HROW 136            // LDS row stride (17x16B) for h1 tile

typedef __bf16 bf16x8 __attribute__((ext_vector_type(8)));
typedef __bf16 bf16x2 __attribute__((ext_vector_type(2)));
typedef float f32x4 __attribute__((ext_vector_type(4)));
typedef float f32x2 __attribute__((ext_vector_type(2)));

// fp8 e4m3 (OCP) helpers — HW converts on gfx950
__device__ inline unsigned char f32_to_fp8(float x) {
    int pk = __builtin_amdgcn_cvt_pk_fp8_f32(x, x, 0, false);
    return (unsigned char)(pk & 0xff);
}
// word-select operand must be a compile-time constant (round-6 lesson)
template <bool HI>
__device__ inline f32x2 fp8x2_to_f32(unsigned int us) {
    return __builtin_amdgcn_cvt_pk_f32_fp8(us, HI);
}
__device__ inline f32x2 fp8x2_to_f32_us(unsigned short us) {
    return __builtin_amdgcn_cvt_pk_f32_fp8((unsigned int)us, false);
}

// ---------------- W -> bf16 B-fragment pack; zero pooled/gcur; graph bounds ----------------
__global__ void k_prepW(const float* __restrict__ Wa, const float* __restrict__ Wb,
                        __bf16* __restrict__ WfA, __bf16* __restrict__ WfB,
                        float* __restrict__ pooled,
                        int* __restrict__ gcur,
                        const int* __restrict__ batch, int* __restrict__ gstart, int N) {
    int gid = blockIdx.x * 256 + threadIdx.x;   // 0..33023
    if (gid < NUM_GRAPHS * D) pooled[gid] = 0.f;
    if (gid < 512) gcur[gid] = 0;
    if (gid >= 16384 && gid <= 16384 + NUM_GRAPHS) {   // 65 threads do binary search
        int g = gid - 16384;
        int lo = 0, hi = N;
        while (lo < hi) { int mid = (lo + hi) >> 1; if (batch[mid] < g) lo = mid + 1; else hi = mid; }
        gstart[g] = lo;
    }
    if (gid >= 32768) return;
    const float* W = (gid < 16384) ? Wa : Wb;
    __bf16* Wf = (gid < 16384) ? WfA : WfB;
    int idx = gid & 16383;
    int j = idx & 7, lane = (idx >> 3) & 63, kc = (idx >> 9) & 3, ft = idx >> 11;
    int k = kc * 32 + (lane >> 4) * 8 + j;
    int f = ft * 16 + (lane & 15);
    Wf[idx] = (__bf16)W[k * D + f];
}

// ---------------- MFMA GEMM body: Y8[N,128](fp8) = X[N,128] @ W  (UNSCALED) ----------------
template <typename T>
__device__ __forceinline__ void gemm_body(int bid, int tid, const T* __restrict__ X,
                                          const __bf16* __restrict__ Wfrag,
                                          unsigned char* __restrict__ Y8, int N) {
    int w = tid >> 6, lane = tid & 63;
    int quad = lane >> 4, m = lane & 15;
    int nodeA = bid * 64 + w * 16 + m;
    if (nodeA >= N) nodeA = N - 1;

    bf16x8 a[4];
#pragma unroll
    for (int kc = 0; kc < 4; kc++) {
        int kb = kc * 32 + quad * 8;
        if constexpr (sizeof(T) == 4) {
            f32x4 x0 = *(const f32x4*)(X + (size_t)nodeA * D + kb);
            f32x4 x1 = *(const f32x4*)(X + (size_t)nodeA * D + kb + 4);
#pragma unroll
            for (int j = 0; j < 4; j++) { a[kc][j] = (__bf16)x0[j]; a[kc][4 + j] = (__bf16)x1[j]; }
        } else {
            a[kc] = *(const bf16x8*)(X + (size_t)nodeA * D + kb);
        }
    }

    f32x4 d[8];
#pragma unroll
    for (int ft = 0; ft < 8; ft++) {
        d[ft] = (f32x4){0.f, 0.f, 0.f, 0.f};
#pragma unroll
        for (int kc = 0; kc < 4; kc++) {
            bf16x8 b = *(const bf16x8*)(Wfrag + (((ft << 2) | kc) * 64 + lane) * 8);
            d[ft] = __builtin_amdgcn_mfma_f32_16x16x32_bf16(a[kc], b, d[ft], 0, 0, 0);
        }
    }

#pragma unroll
    for (int r = 0; r < 4; r++) {
        int node = bid * 64 + w * 16 + quad * 4 + r;
        if (node < N) {
#pragma unroll
            for (int ft = 0; ft < 8; ft++)
                Y8[(size_t)node * D + ft * 16 + m] = f32_to_fp8(d[ft][r]);
        }
    }
}

// ---------------- FUSED: CSR bin pass (blocks [0,nchunk)) + layer-1 GEMM (rest) ----------------
__launch_bounds__(256)
__global__ void k_bin_gemm(const int* __restrict__ ei, int* __restrict__ gcur,
                           int* __restrict__ bbuf, int nbuck, int E, int nchunk,
                           const float* __restrict__ X, const __bf16* __restrict__ Wfrag,
                           unsigned char* __restrict__ Y8, int N) {
    __shared__ int h[512];
    __shared__ int base[512];

    if (blockIdx.x >= nchunk) {
        gemm_body<float>(blockIdx.x - nchunk, threadIdx.x, X, Wfrag, Y8, N);
        return;
    }

    int tid = threadIdx.x;
    for (int b = tid; b < nbuck; b += 256) h[b] = 0;
    __syncthreads();
    int lo = blockIdx.x * CHUNK;
    if (lo + CHUNK <= E) {
        const int4* c4 = (const int4*)(ei + E + lo);
#pragma unroll 2
        for (int i = tid; i < CHUNK / 4; i += 256) {
            int4 c = c4[i];
            atomicAdd(&h[c.x >> BUCK_SH], 1);
            atomicAdd(&h[c.y >> BUCK_SH], 1);
            atomicAdd(&h[c.z >> BUCK_SH], 1);
            atomicAdd(&h[c.w >> BUCK_SH], 1);
        }
    } else {
        for (int i = tid; i < CHUNK; i += 256) {
            int e = lo + i;
            if (e < E) atomicAdd(&h[ei[E + e] >> BUCK_SH], 1);
        }
    }
    __syncthreads();
    for (int b = tid; b < nbuck; b += 256) {
        base[b] = atomicAdd(&gcur[b], h[b]);
        h[b] = 0;
    }
    __syncthreads();
    if (lo + CHUNK <= E) {
        const int4* r4 = (const int4*)(ei + lo);
        const int4* c4 = (const int4*)(ei + E + lo);
#pragma unroll 2
        for (int i = tid; i < CHUNK / 4; i += 256) {
            int4 r = r4[i];
            int4 c = c4[i];
            int rr[4] = {r.x, r.y, r.z, r.w};
            int cc[4] = {c.x, c.y, c.z, c.w};
#pragma unroll
            for (int u = 0; u < 4; u++) {
                int b = cc[u] >> BUCK_SH;
                int pos = base[b] + atomicAdd(&h[b], 1);
                if (pos < BCAP) bbuf[(size_t)b * BCAP + pos] = rr[u] | ((cc[u] & (BUCK_N - 1)) << 17);
            }
        }
    } else {
        for (int i = tid; i < CHUNK; i += 256) {
            int e = lo + i;
            if (e < E) {
                int r = ei[e], c = ei[E + e];
                int b = c >> BUCK_SH;
                int pos = base[b] + atomicAdd(&h[b], 1);
                if (pos < BCAP) bbuf[(size_t)b * BCAP + pos] = r | ((c & (BUCK_N - 1)) << 17);
            }
        }
    }
}

// ---------------- CSR build pass 2 + IN-PLACE z1 SCALING (r8-proven: agg_gemm 85->61) ----------------
__global__ void k_place(const int* __restrict__ bbuf, const int* __restrict__ gcur,
                        int* __restrict__ esrc,
                        int* __restrict__ cnt, int* __restrict__ offs,
                        float* __restrict__ dis, unsigned char* __restrict__ z1, int N) {
    __shared__ int h[256];
    __shared__ int sc[256];
    __shared__ int cur[256];
    __shared__ float sdis[256];
    int b = blockIdx.x, tid = threadIdx.x;
    int start = b * BCAP;
    int count = gcur[b]; if (count > BCAP) count = BCAP;
    int end = start + count;
    h[tid] = 0;
    __syncthreads();
    for (int i = start + tid; i < end; i += 256) atomicAdd(&h[(bbuf[i] >> 17) & 255], 1);
    __syncthreads();
    int local = h[tid];
    sc[tid] = local;
    __syncthreads();
    for (int off = 1; off < 256; off <<= 1) {
        int xv = (tid >= off) ? sc[tid - off] : 0;
        __syncthreads();
        sc[tid] += xv;
        __syncthreads();
    }
    int excl = sc[tid] - local;
    cur[tid] = start + excl;
    int c = b * 256 + tid;
    float dv = rsqrtf(1.0f + (float)local);
    sdis[tid] = dv;
    if (c < N) {
        cnt[c]  = local;
        offs[c] = start + excl;
        dis[c]  = dv;                        // deg includes self-loop
    }
    __syncthreads();
    for (int i = start + tid; i < end; i += 256) {
        int p = bbuf[i];
        int pos = atomicAdd(&cur[(p >> 17) & 255], 1);
        esrc[pos] = p & 0x1FFFF;
    }
    // ---- in-place scale of this bucket's z1 rows ----
    int nrows = N - b * 256; if (nrows > 256) nrows = 256; if (nrows < 0) nrows = 0;
    unsigned int* zp = (unsigned int*)(z1 + (size_t)b * 256 * D);
    for (int i = tid; i < nrows * 32; i += 256) {      // 32 dwords per 128B row
        int row = i >> 5;
        float s = sdis[row];
        unsigned int v = zp[i];
        f32x2 lo = fp8x2_to_f32<false>(v);
        f32x2 hi = fp8x2_to_f32<true>(v);
        unsigned int u = (unsigned int)__builtin_amdgcn_cvt_pk_fp8_f32(lo[0] * s, lo[1] * s, 0, false);
        u = (unsigned int)__builtin_amdgcn_cvt_pk_fp8_f32(hi[0] * s, hi[1] * s, (int)u, true);
        zp[i] = u;
    }
}

// ---------------- FUSED layer-1 agg + GEMM2: z2 = fp8(dis .* (leaky(agg(z1)+b1) @ W2)) ----------------
__launch_bounds__(256)
__global__ void k_agg_gemm(const unsigned char* __restrict__ Hs8,      // z1 scaled fp8
                           const int* __restrict__ offs, const int* __restrict__ cnt,
                           const float* __restrict__ dis, const int* __restrict__ esrc,
                           const float* __restrict__ bias,             // b1
                           const __bf16* __restrict__ Wfrag,           // Wf2
                           unsigned char* __restrict__ Y8, int N) {    // z2 scaled fp8
    __shared__ __bf16 hl[32 * HROW];   // 32 nodes x 128 feats, padded rows (17x16B)
    int tid = threadIdx.x;
    int w = tid >> 6, lane = tid & 63;
    int node0 = blockIdx.x * 32 + w * 8;
    float b0 = bias[lane * 2], b1v = bias[lane * 2 + 1];

    for (int nn = 0; nn < 8; nn++) {
        int node = node0 + nn;
        if (node < N) {
            int start = offs[node];
            int len = cnt[node];
            float di = dis[node];
            f32x2 h = fp8x2_to_f32_us(*(const unsigned short*)(Hs8 + (size_t)node * D + lane * 2));
            float acc0 = h[0];               // self-loop term (already dis-scaled)
            float acc1 = h[1];

            for (int k0 = 0; k0 < len; k0 += 64) {
                int mm = len - k0; if (mm > 64) mm = 64;
                int ep = esrc[start + k0 + (lane < mm ? lane : 0)];
                int j = 0;
                for (; j + 16 <= mm; j += 16) {
                    int s[16]; unsigned short hv[16];
#pragma unroll
                    for (int u = 0; u < 16; u++) s[u] = __shfl(ep, j + u);
#pragma unroll
                    for (int u = 0; u < 16; u++) hv[u] = *(const unsigned short*)(Hs8 + (size_t)s[u] * D + lane * 2);
#pragma unroll
                    for (int u = 0; u < 16; u++) { f32x2 f = fp8x2_to_f32_us(hv[u]); acc0 += f[0]; acc1 += f[1]; }
                }
                for (; j + 4 <= mm; j += 4) {
                    int s[4]; unsigned short hv[4];
#pragma unroll
                    for (int u = 0; u < 4; u++) s[u] = __shfl(ep, j + u);
#pragma unroll
                    for (int u = 0; u < 4; u++) hv[u] = *(const unsigned short*)(Hs8 + (size_t)s[u] * D + lane * 2);
#pragma unroll
                    for (int u = 0; u < 4; u++) { f32x2 f = fp8x2_to_f32_us(hv[u]); acc0 += f[0]; acc1 += f[1]; }
                }
                for (; j < mm; j++) {
                    int s = __shfl(ep, j);
                    f32x2 f = fp8x2_to_f32_us(*(const unsigned short*)(Hs8 + (size_t)s * D + lane * 2));
                    acc0 += f[0]; acc1 += f[1];
                }
            }

            acc0 = acc0 * di + b0;
            acc1 = acc1 * di + b1v;
            acc0 = acc0 >= 0.f ? acc0 : 0.01f * acc0;
            acc1 = acc1 >= 0.f ? acc1 : 0.01f * acc1;
            bf16x2 o; o[0] = (__bf16)acc0; o[1] = (__bf16)acc1;
            *(bf16x2*)&hl[(w * 8 + nn) * HROW + lane * 2] = o;   // h1 -> LDS only
        } else {
            bf16x2 z; z[0] = (__bf16)0.f; z[1] = (__bf16)0.f;
            *(bf16x2*)&hl[(w * 8 + nn) * HROW + lane * 2] = z;
        }
    }
    __syncthreads();

    // ---- MFMA phase: wave w -> row tile (w&1)*16, ft half (w>>1)*4 ----
    int quad = lane >> 4, m = lane & 15;
    int rtile = w & 1, fthalf = w >> 1;
    int lrow = rtile * 16 + m;
    bf16x8 a[4];
#pragma unroll
    for (int kc = 0; kc < 4; kc++)
        a[kc] = *(const bf16x8*)&hl[lrow * HROW + kc * 32 + quad * 8];

    int nb = blockIdx.x * 32 + rtile * 16 + quad * 4;
    float scv[4];
#pragma unroll
    for (int r = 0; r < 4; r++) scv[r] = (nb + r < N) ? dis[nb + r] : 0.f;

#pragma unroll
    for (int ft = 0; ft < 4; ft++) {
        int gft = fthalf * 4 + ft;
        f32x4 dacc = (f32x4){0.f, 0.f, 0.f, 0.f};
#pragma unroll
        for (int kc = 0; kc < 4; kc++) {
            bf16x8 b = *(const bf16x8*)(Wfrag + (((gft << 2) | kc) * 64 + lane) * 8);
            dacc = __builtin_amdgcn_mfma_f32_16x16x32_bf16(a[kc], b, dacc, 0, 0, 0);
        }
#pragma unroll
        for (int r = 0; r < 4; r++) {
            int node = nb + r;
            if (node < N)
                Y8[(size_t)node * D + gft * 16 + m] = f32_to_fp8(dacc[r] * scv[r]);
        }
    }
}

// ---------------- layer-2 CSR aggregation + bias + leaky ReLU (r0 lean loop) ----------------
__launch_bounds__(256)
__global__ void k_agg(const unsigned char* __restrict__ Hs8, __bf16* __restrict__ O,
                      const int* __restrict__ offs, const int* __restrict__ cnt,
                      const float* __restrict__ dis, const int* __restrict__ esrc,
                      const float* __restrict__ bias, int N) {
    int wave = (blockIdx.x * 256 + threadIdx.x) >> 6;
    int lane = threadIdx.x & 63;
    int node0 = wave * 8;
    float b0 = bias[lane * 2], b1 = bias[lane * 2 + 1];

    for (int nn = 0; nn < 8; nn++) {
        int node = node0 + nn;
        if (node >= N) return;
        int start = offs[node];
        int len = cnt[node];
        float di = dis[node];
        f32x2 h = fp8x2_to_f32_us(*(const unsigned short*)(Hs8 + (size_t)node * D + lane * 2));
        float acc0 = h[0];               // self-loop term (already dis-scaled)
        float acc1 = h[1];

        for (int k0 = 0; k0 < len; k0 += 64) {
            int mm = len - k0; if (mm > 64) mm = 64;
            int ep = esrc[start + k0 + (lane < mm ? lane : 0)];
            int j = 0;
            for (; j + 16 <= mm; j += 16) {
                int s[16]; unsigned short hv[16];
#pragma unroll
                for (int u = 0; u < 16; u++) s[u] = __shfl(ep, j + u);
#pragma unroll
                for (int u = 0; u < 16; u++) hv[u] = *(const unsigned short*)(Hs8 + (size_t)s[u] * D + lane * 2);
#pragma unroll
                for (int u = 0; u < 16; u++) { f32x2 f = fp8x2_to_f32_us(hv[u]); acc0 += f[0]; acc1 += f[1]; }
            }
            for (; j + 4 <= mm; j += 4) {
                int s[4]; unsigned short hv[4];
#pragma unroll
                for (int u = 0; u < 4; u++) s[u] = __shfl(ep, j + u);
#pragma unroll
                for (int u = 0; u < 4; u++) hv[u] = *(const unsigned short*)(Hs8 + (size_t)s[u] * D + lane * 2);
#pragma unroll
                for (int u = 0; u < 4; u++) { f32x2 f = fp8x2_to_f32_us(hv[u]); acc0 += f[0]; acc1 += f[1]; }
            }
            for (; j < mm; j++) {
                int s = __shfl(ep, j);
                f32x2 f = fp8x2_to_f32_us(*(const unsigned short*)(Hs8 + (size_t)s * D + lane * 2));
                acc0 += f[0]; acc1 += f[1];
            }
        }

        acc0 = acc0 * di + b0;
        acc1 = acc1 * di + b1;
        acc0 = acc0 >= 0.f ? acc0 : 0.01f * acc0;
        acc1 = acc1 >= 0.f ? acc1 : 0.01f * acc1;
        bf16x2 o; o[0] = (__bf16)acc0; o[1] = (__bf16)acc1;
        *(bf16x2*)(O + (size_t)node * D + lane * 2) = o;
    }
}

// ---------------- pooling: per-graph-slice vectorized reduction (NO fence — r8 lesson) ----------------
__launch_bounds__(256)
__global__ void k_pool(const __bf16* __restrict__ H, const int* __restrict__ gstart,
                       float* __restrict__ pooled) {
    __shared__ float sdata[256 * 9];
    int g = blockIdx.x / PSLICE;
    int slice = blockIdx.x - g * PSLICE;
    int gs = gstart[g], ge = gstart[g + 1];
    int cg = ge - gs;
    int r0 = gs + (int)((long long)cg * slice / PSLICE);
    int r1 = gs + (int)((long long)cg * (slice + 1) / PSLICE);
    int t = threadIdx.x;
    int rg = t >> 4, fb = t & 15;

    float acc[8];
#pragma unroll
    for (int j = 0; j < 8; j++) acc[j] = 0.f;
    for (int r = r0 + rg; r < r1; r += 16) {
        bf16x8 v = *(const bf16x8*)(H + (size_t)r * D + fb * 8);
#pragma unroll
        for (int j = 0; j < 8; j++) acc[j] += (float)v[j];
    }
#pragma unroll
    for (int j = 0; j < 8; j++) sdata[t * 9 + j] = acc[j];
    __syncthreads();
#pragma unroll
    for (int s = 128; s >= 16; s >>= 1) {
        if (t < s) {
#pragma unroll
            for (int j = 0; j < 8; j++) sdata[t * 9 + j] += sdata[(t + s) * 9 + j];
        }
        __syncthreads();
    }
    if (t < 16) {
#pragma unroll
        for (int j = 0; j < 8; j++) atomicAdd(&pooled[g * D + t * 8 + j], sdata[t * 9 + j]);
    }
}

// ---------------- tiny final FC: out[g] = (pooled[g,:] . fcW)/cnt_g + fcb ----------------
__launch_bounds__(64)
__global__ void k_fc(const float* __restrict__ pooled, const int* __restrict__ gstart,
                     const float* __restrict__ fcW, const float* __restrict__ fcb,
                     float* __restrict__ out) {
    int t = threadIdx.x;   // 64 threads, one graph each
    float s = 0.f;
#pragma unroll 8
    for (int k = 0; k < D; k += 4) {
        f32x4 pv = *(const f32x4*)(pooled + t * D + k);
        f32x4 wv = *(const f32x4*)(fcW + k);
        s += pv[0] * wv[0] + pv[1] * wv[1] + pv[2] * wv[2] + pv[3] * wv[3];
    }
    float c = (float)(gstart[t + 1] - gstart[t]);
    out[t] = s / fmaxf(c, 1.0f) + fcb[0];
}

extern "C" void kernel_launch(void* const* d_in, const int* in_sizes, int n_in,
                              void* d_out, int out_size, void* d_ws, size_t ws_size,
                              hipStream_t stream) {
    const float* x    = (const float*)d_in[0];
    const int*   ei   = (const int*)d_in[1];
    const int*   batch= (const int*)d_in[2];
    const float* W1   = (const float*)d_in[3];
    const float* b1   = (const float*)d_in[4];
    const float* W2   = (const float*)d_in[5];
    const float* b2   = (const float*)d_in[6];
    const float* fcW  = (const float*)d_in[7];
    const float* fcb  = (const float*)d_in[8];
    float* out = (float*)d_out;

    int N = in_sizes[0] / D;
    int E = in_sizes[1] / 2;

    int NBUCK  = (N + BUCK_N - 1) >> BUCK_SH;  // 391 for N=100000 (<=512)
    int NCHUNK = (E + CHUNK - 1) / CHUNK;      // 196 for E=1.6M

    char* p = (char*)d_ws;
    auto alloc = [&](size_t bytes) { char* r = p; p += (bytes + 255) & ~(size_t)255; return r; };
    int*    cnt    = (int*)   alloc((size_t)N * 4);
    int*    offs   = (int*)   alloc((size_t)N * 4);
    float*  dis    = (float*) alloc((size_t)N * 4);
    int*    gcur   = (int*)   alloc(512 * 4);
    int*    bbuf   = (int*)   alloc((size_t)NBUCK * BCAP * 4);
    int*    esrc   = (int*)   alloc((size_t)NBUCK * BCAP * 4);
    unsigned char* bufA8 = (unsigned char*)alloc((size_t)(NBUCK * BUCK_N) * D); // z1 fp8 (scaled in place)
    unsigned char* bufC8 = (unsigned char*)alloc((size_t)N * D);   // z2 fp8 (scaled)
    __bf16* bufB   = (__bf16*)alloc((size_t)N * D * 2);            // h2 bf16
    __bf16* Wf1    = (__bf16*)alloc((size_t)D * D * 2);
    __bf16* Wf2    = (__bf16*)alloc((size_t)D * D * 2);
    float*  pooled = (float*) alloc((size_t)NUM_GRAPHS * D * 4);
    int*    gstart = (int*)   alloc((NUM_GRAPHS + 1) * 4);

    int gblocks = (N + 63) / 64;
    int ablocks = (N + 31) / 32;     // agg kernels: 4 waves/block x 8 nodes/wave

    // prep: zeroes gcur/pooled, packs W, graph boundaries
    k_prepW<<<129, 256, 0, stream>>>(W1, W2, Wf1, Wf2, pooled, gcur, batch, gstart, N);

    // FUSED: CSR bin (196 blocks) runs concurrently with layer-1 GEMM (1563 blocks)
    k_bin_gemm<<<NCHUNK + gblocks, 256, 0, stream>>>(ei, gcur, bbuf, NBUCK, E, NCHUNK,
                                                     x, Wf1, bufA8, N);
    // CSR place + in-place dis-scaling of z1 rows (bucket b owns nodes 256b..)
    k_place<<<NBUCK, 256, 0, stream>>>(bbuf, gcur, esrc, cnt, offs, dis, bufA8, N);

    // FUSED layer-1 agg + GEMM2: bufC8 = fp8(dis .* (leaky(agg(bufA8)+b1) @ W2))
    k_agg_gemm<<<ablocks, 256, 0, stream>>>(bufA8, offs, cnt, dis, esrc, b1, Wf2, bufC8, N);

    // layer-2 agg (lean): bufB = leaky(agg(bufC8)+b2)
    k_agg<<<ablocks, 256, 0, stream>>>(bufC8, bufB, offs, cnt, dis, esrc, b2, N);

    // pool (fence-free) + tiny FC (separate dispatch guarantees atomic visibility)
    k_pool<<<NUM_GRAPHS * PSLICE, 256, 0, stream>>>(bufB, gstart, pooled);
    k_fc<<<1, 64, 0, stream>>>(pooled, gstart, fcW, fcb, out);
}